// Round 1
// baseline (716.428 us; speedup 1.0000x reference)
//
#include <hip/hip_runtime.h>
#include <math.h>

#define F_IN  512
#define F_HID 256
#define F_OUT 64

// ---------------- degree / normalization ----------------
__global__ void k_deg(const int* __restrict__ dst, int* __restrict__ deg, int E) {
    int e = blockIdx.x * 256 + threadIdx.x;
    if (e < E) atomicAdd(&deg[dst[e]], 1);
}

__global__ void k_dinv(const int* __restrict__ deg, float* __restrict__ dinv, int N) {
    int i = blockIdx.x * 256 + threadIdx.x;
    if (i < N) dinv[i] = rsqrtf((float)(deg[i] + 1));  // +1 self loop
}

// ---------------- 2-level exclusive scan (chunk = 256) ----------------
__global__ void k_scan1(const int* __restrict__ deg, int* __restrict__ offs,
                        int* __restrict__ bsums, int N) {
    __shared__ int s[256];
    int tid = threadIdx.x;
    int i = blockIdx.x * 256 + tid;
    int v = (i < N) ? deg[i] : 0;
    s[tid] = v; __syncthreads();
    for (int d = 1; d < 256; d <<= 1) {
        int t = (tid >= d) ? s[tid - d] : 0;
        __syncthreads();
        s[tid] += t;
        __syncthreads();
    }
    if (i < N) offs[i] = s[tid] - v;         // exclusive within chunk
    if (tid == 255) bsums[blockIdx.x] = s[255];
}

__global__ void k_scan2(int* __restrict__ bsums, int n) {
    __shared__ int s[256];
    int tid = threadIdx.x;
    int v = (tid < n) ? bsums[tid] : 0;
    s[tid] = v; __syncthreads();
    for (int d = 1; d < 256; d <<= 1) {
        int t = (tid >= d) ? s[tid - d] : 0;
        __syncthreads();
        s[tid] += t;
        __syncthreads();
    }
    if (tid < n) bsums[tid] = s[tid] - v;    // exclusive chunk bases
}

__global__ void k_scan3(int* __restrict__ offs, const int* __restrict__ bsums,
                        int* __restrict__ cursor, int N, int E) {
    int i = blockIdx.x * 256 + threadIdx.x;
    if (i < N) {
        int o = offs[i] + bsums[i >> 8];
        offs[i] = o;
        cursor[i] = o;
    }
    if (i == 0) offs[N] = E;
}

__global__ void k_fill(const int* __restrict__ src, const int* __restrict__ dst,
                       int* __restrict__ cursor, int* __restrict__ csr, int E) {
    int e = blockIdx.x * 256 + threadIdx.x;
    if (e < E) {
        int pos = atomicAdd(&cursor[dst[e]], 1);
        csr[pos] = src[e];
    }
}

// ---------------- fp32 tiled GEMM: C[M,Nc] = A[M,K] @ B[K,Nc] ----------------
// BM=BN=64, BK=16, 256 threads, 4x4 per thread. K%16==0, Nc%64==0 assumed.
__global__ void k_gemm(const float* __restrict__ A, const float* __restrict__ B,
                       float* __restrict__ C, int M, int K, int Nc) {
    __shared__ float As[64][17];
    __shared__ float Bs[16][65];
    int tid = threadIdx.x;
    int tx = tid & 15, ty = tid >> 4;
    int m0 = blockIdx.y * 64, n0 = blockIdx.x * 64;
    float acc[4][4] = {};
    for (int k0 = 0; k0 < K; k0 += 16) {
        #pragma unroll
        for (int l = 0; l < 4; ++l) {
            int idx = tid + l * 256;
            int r = idx >> 4, c = idx & 15;
            int gr = m0 + r;
            As[r][c] = (gr < M) ? A[(size_t)gr * K + k0 + c] : 0.f;
        }
        #pragma unroll
        for (int l = 0; l < 4; ++l) {
            int idx = tid + l * 256;
            int r = idx >> 6, c = idx & 63;
            Bs[r][c] = B[(size_t)(k0 + r) * Nc + n0 + c];
        }
        __syncthreads();
        #pragma unroll
        for (int k = 0; k < 16; ++k) {
            float a[4], b[4];
            #pragma unroll
            for (int i = 0; i < 4; ++i) a[i] = As[ty * 4 + i][k];
            #pragma unroll
            for (int j = 0; j < 4; ++j) b[j] = Bs[k][tx * 4 + j];
            #pragma unroll
            for (int i = 0; i < 4; ++i)
                #pragma unroll
                for (int j = 0; j < 4; ++j) acc[i][j] += a[i] * b[j];
        }
        __syncthreads();
    }
    #pragma unroll
    for (int i = 0; i < 4; ++i) {
        int gr = m0 + ty * 4 + i;
        if (gr < M) {
            #pragma unroll
            for (int j = 0; j < 4; ++j)
                C[(size_t)gr * Nc + n0 + tx * 4 + j] = acc[i][j];
        }
    }
}

// ---------------- layer-1 aggregation: block per node, thread = feature ----------------
__global__ void k_agg1(const float* __restrict__ h, const int* __restrict__ csr,
                       const int* __restrict__ offs, const float* __restrict__ dinv,
                       const float* __restrict__ bias, float* __restrict__ outm) {
    int i = blockIdx.x;
    int f = threadIdx.x;
    float di = dinv[i];
    float acc = h[(size_t)i * F_HID + f] * di * di;   // self loop
    int s = offs[i], e = offs[i + 1];
    for (int idx = s; idx < e; ++idx) {
        int j = csr[idx];
        acc += h[(size_t)j * F_HID + f] * (dinv[j] * di);
    }
    outm[(size_t)i * F_HID + f] = fmaxf(acc + bias[f], 0.f);
}

// ---------------- layer-2 aggregation + bias + log_softmax: wave per node ----------------
__global__ void k_agg2(const float* __restrict__ h, const int* __restrict__ csr,
                       const int* __restrict__ offs, const float* __restrict__ dinv,
                       const float* __restrict__ bias, float* __restrict__ outm, int N) {
    int warp = threadIdx.x >> 6, lane = threadIdx.x & 63;
    int i = blockIdx.x * 4 + warp;
    if (i >= N) return;
    float di = dinv[i];
    float acc = h[(size_t)i * F_OUT + lane] * di * di;
    int s = offs[i], e = offs[i + 1];
    for (int idx = s; idx < e; ++idx) {
        int j = csr[idx];
        acc += h[(size_t)j * F_OUT + lane] * (dinv[j] * di);
    }
    acc += bias[lane];
    float m = acc;
    #pragma unroll
    for (int o = 32; o >= 1; o >>= 1) m = fmaxf(m, __shfl_xor(m, o, 64));
    float ex = expf(acc - m);
    float ssum = ex;
    #pragma unroll
    for (int o = 32; o >= 1; o >>= 1) ssum += __shfl_xor(ssum, o, 64);
    outm[(size_t)i * F_OUT + lane] = acc - m - logf(ssum);
}

extern "C" void kernel_launch(void* const* d_in, const int* in_sizes, int n_in,
                              void* d_out, int out_size, void* d_ws, size_t ws_size,
                              hipStream_t stream) {
    const float* x  = (const float*)d_in[0];
    const int*   ei = (const int*)d_in[1];
    const float* W1 = (const float*)d_in[2];
    const float* b1 = (const float*)d_in[3];
    const float* W2 = (const float*)d_in[4];
    const float* b2 = (const float*)d_in[5];
    float* out = (float*)d_out;

    int N = in_sizes[0] / F_IN;   // 50000
    int E = in_sizes[1] / 2;      // 800000
    const int* src = ei;
    const int* dst = ei + E;

    // workspace layout
    float* h1   = (float*)d_ws;                       // N*F_HID (later reused as h2)
    float* a1   = h1 + (size_t)N * F_HID;             // N*F_HID
    int*   deg  = (int*)(a1 + (size_t)N * F_HID);     // N
    float* dinv = (float*)(deg + N);                  // N
    int*   offs = (int*)(dinv + N);                   // N+1
    int*   cursor = offs + N + 1;                     // N
    int*   bsums  = cursor + N;                       // <=256
    int*   csr    = bsums + 256;                      // E
    float* h2 = h1;                                   // reuse after agg1

    int nch = (N + 255) / 256;

    hipMemsetAsync(deg, 0, sizeof(int) * N, stream);
    k_deg <<<(E + 255) / 256, 256, 0, stream>>>(dst, deg, E);
    k_dinv<<<(N + 255) / 256, 256, 0, stream>>>(deg, dinv, N);
    k_scan1<<<nch, 256, 0, stream>>>(deg, offs, bsums, N);
    k_scan2<<<1, 256, 0, stream>>>(bsums, nch);
    k_scan3<<<nch, 256, 0, stream>>>(offs, bsums, cursor, N, E);
    k_fill<<<(E + 255) / 256, 256, 0, stream>>>(src, dst, cursor, csr, E);

    // layer 1
    k_gemm<<<dim3(F_HID / 64, (N + 63) / 64), 256, 0, stream>>>(x, W1, h1, N, F_IN, F_HID);
    k_agg1<<<N, 256, 0, stream>>>(h1, csr, offs, dinv, b1, a1);

    // layer 2
    k_gemm<<<dim3(F_OUT / 64, (N + 63) / 64), 256, 0, stream>>>(a1, W2, h2, N, F_HID, F_OUT);
    k_agg2<<<(N + 3) / 4, 256, 0, stream>>>(h2, csr, offs, dinv, b2, out, N);
}

// Round 2
// 429.819 us; speedup vs baseline: 1.6668x; 1.6668x over previous
//
#include <hip/hip_runtime.h>
#include <math.h>

#define F_IN  512
#define F_HID 256
#define F_OUT 64

typedef __attribute__((ext_vector_type(8))) short bf16x8;
typedef __attribute__((ext_vector_type(4))) float f32x4;

#define GLOBAL_AS __attribute__((address_space(1)))
#define LDS_AS    __attribute__((address_space(3)))

__device__ __forceinline__ void gload_lds16(const ushort* g, ushort* l) {
    __builtin_amdgcn_global_load_lds((const GLOBAL_AS uint32_t*)g,
                                     (LDS_AS uint32_t*)l, 16, 0, 0);
}

__device__ __forceinline__ ushort f2bf(float f) {
    union { float f; uint32_t u; } v; v.f = f;
    uint32_t r = (v.u + 0x7FFFu + ((v.u >> 16) & 1u)) >> 16;
    return (ushort)r;
}

// ---------------- degree / normalization ----------------
__global__ void k_deg(const int* __restrict__ dst, int* __restrict__ deg, int E) {
    int e = blockIdx.x * 256 + threadIdx.x;
    if (e < E) atomicAdd(&deg[dst[e]], 1);
}

__global__ void k_dinv(const int* __restrict__ deg, float* __restrict__ dinv, int N) {
    int i = blockIdx.x * 256 + threadIdx.x;
    if (i < N) dinv[i] = rsqrtf((float)(deg[i] + 1));  // +1 self loop
}

// ---------------- 2-level exclusive scan (chunk = 256) ----------------
__global__ void k_scan1(const int* __restrict__ deg, int* __restrict__ offs,
                        int* __restrict__ bsums, int N) {
    __shared__ int s[256];
    int tid = threadIdx.x;
    int i = blockIdx.x * 256 + tid;
    int v = (i < N) ? deg[i] : 0;
    s[tid] = v; __syncthreads();
    for (int d = 1; d < 256; d <<= 1) {
        int t = (tid >= d) ? s[tid - d] : 0;
        __syncthreads();
        s[tid] += t;
        __syncthreads();
    }
    if (i < N) offs[i] = s[tid] - v;
    if (tid == 255) bsums[blockIdx.x] = s[255];
}

__global__ void k_scan2(int* __restrict__ bsums, int n) {
    __shared__ int s[256];
    int tid = threadIdx.x;
    int v = (tid < n) ? bsums[tid] : 0;
    s[tid] = v; __syncthreads();
    for (int d = 1; d < 256; d <<= 1) {
        int t = (tid >= d) ? s[tid - d] : 0;
        __syncthreads();
        s[tid] += t;
        __syncthreads();
    }
    if (tid < n) bsums[tid] = s[tid] - v;
}

__global__ void k_scan3(int* __restrict__ offs, const int* __restrict__ bsums,
                        int* __restrict__ cursor, int N, int E) {
    int i = blockIdx.x * 256 + threadIdx.x;
    if (i < N) {
        int o = offs[i] + bsums[i >> 8];
        offs[i] = o;
        cursor[i] = o;
    }
    if (i == 0) offs[N] = E;
}

__global__ void k_fill(const int* __restrict__ src, const int* __restrict__ dst,
                       int* __restrict__ cursor, int* __restrict__ csr, int E) {
    int e = blockIdx.x * 256 + threadIdx.x;
    if (e < E) {
        int pos = atomicAdd(&cursor[dst[e]], 1);
        csr[pos] = src[e];
    }
}

// ---------------- casts ----------------
// fp32 -> bf16, 8 elems/thread
__global__ void k_cast_bf16(const float* __restrict__ in, ushort* __restrict__ outp, int n8) {
    int i = blockIdx.x * 256 + threadIdx.x;
    if (i >= n8) return;
    const float4* p = (const float4*)in + (size_t)i * 2;
    float4 v0 = p[0], v1 = p[1];
    bf16x8 o;
    o[0] = (short)f2bf(v0.x); o[1] = (short)f2bf(v0.y);
    o[2] = (short)f2bf(v0.z); o[3] = (short)f2bf(v0.w);
    o[4] = (short)f2bf(v1.x); o[5] = (short)f2bf(v1.y);
    o[6] = (short)f2bf(v1.z); o[7] = (short)f2bf(v1.w);
    *(bf16x8*)&outp[(size_t)i * 8] = o;
}

// in: [K][Nc] fp32  ->  out: [Nc][K] bf16
__global__ void k_tcast(const float* __restrict__ in, ushort* __restrict__ outp, int K, int Nc) {
    int idx = blockIdx.x * 256 + threadIdx.x;
    if (idx >= K * Nc) return;
    int n = idx / K, k = idx - n * K;
    outp[idx] = f2bf(in[(size_t)k * Nc + n]);
}

// ---------------- bf16 MFMA GEMM: C[M,Nc] = A[M,K] @ Bt[Nc,K]^T ----------------
// BK=32, 4 waves (256 thr). Wave grid WR x WC, per-wave fragment grid MR x NR.
// BM = WR*MR*16, BN = WC*NR*16. K % 32 == 0, Nc % BN == 0 required.
template<int WR, int WC, int MR, int NR>
__global__ __launch_bounds__(256) void k_gemm_bf16(
        const ushort* __restrict__ A, const ushort* __restrict__ Bt,
        float* __restrict__ C, int M, int K, int Nc) {
    constexpr int BM = WR * MR * 16;
    constexpr int BN = WC * NR * 16;
    __shared__ ushort As[BM * 32];
    __shared__ ushort Bs[BN * 32];
    const int tid  = threadIdx.x;
    const int wave = tid >> 6, lane = tid & 63;
    const int wr = wave % WR, wc = wave / WR;
    const int brow = blockIdx.y * BM, bcol = blockIdx.x * BN;

    f32x4 acc[MR][NR];
    #pragma unroll
    for (int m = 0; m < MR; ++m)
        #pragma unroll
        for (int n = 0; n < NR; ++n) acc[m][n] = (f32x4){0.f, 0.f, 0.f, 0.f};

    const int srow = tid >> 2;          // 0..63: row within a 64-row staging group
    const int scol = (tid & 3) * 8;     // k-offset of this thread's 16B chunk
    const int kq  = (lane >> 4) * 8;    // fragment k-offset
    const int rA0 = wr * MR * 16 + (lane & 15);
    const int rB0 = wc * NR * 16 + (lane & 15);

    for (int k0 = 0; k0 < K; k0 += 32) {
        #pragma unroll
        for (int l = 0; l < BM / 64; ++l) {
            int row = brow + l * 64 + srow;
            if (row >= M) row = M - 1;                 // clamp: keeps addr in-bounds
            gload_lds16(&A[(size_t)row * K + k0 + scol], &As[l * 2048 + wave * 512]);
        }
        #pragma unroll
        for (int l = 0; l < BN / 64; ++l) {
            int row = bcol + l * 64 + srow;            // always < Nc
            gload_lds16(&Bt[(size_t)row * K + k0 + scol], &Bs[l * 2048 + wave * 512]);
        }
        __syncthreads();
        bf16x8 af[MR], bf[NR];
        #pragma unroll
        for (int m = 0; m < MR; ++m)
            af[m] = *(const bf16x8*)&As[(rA0 + m * 16) * 32 + kq];
        #pragma unroll
        for (int n = 0; n < NR; ++n)
            bf[n] = *(const bf16x8*)&Bs[(rB0 + n * 16) * 32 + kq];
        #pragma unroll
        for (int m = 0; m < MR; ++m)
            #pragma unroll
            for (int n = 0; n < NR; ++n)
                acc[m][n] = __builtin_amdgcn_mfma_f32_16x16x32_bf16(af[m], bf[n], acc[m][n], 0, 0, 0);
        __syncthreads();
    }

    const int crow0 = brow + wr * MR * 16 + (lane >> 4) * 4;
    const int ccol0 = bcol + wc * NR * 16 + (lane & 15);
    #pragma unroll
    for (int m = 0; m < MR; ++m)
        #pragma unroll
        for (int n = 0; n < NR; ++n)
            #pragma unroll
            for (int j = 0; j < 4; ++j) {
                int row = crow0 + m * 16 + j;
                if (row < M) C[(size_t)row * Nc + ccol0 + n * 16] = acc[m][n][j];
            }
}

// ---------------- layer-1 aggregation: block per node, thread = feature ----------------
// reads fp32 h, writes bf16 (feeds bf16 GEMM2)
__global__ void k_agg1(const float* __restrict__ h, const int* __restrict__ csr,
                       const int* __restrict__ offs, const float* __restrict__ dinv,
                       const float* __restrict__ bias, ushort* __restrict__ outm) {
    int i = blockIdx.x;
    int f = threadIdx.x;
    float di = dinv[i];
    float acc = h[(size_t)i * F_HID + f] * di * di;   // self loop
    int s = offs[i], e = offs[i + 1];
    for (int idx = s; idx < e; ++idx) {
        int j = csr[idx];
        acc += h[(size_t)j * F_HID + f] * (dinv[j] * di);
    }
    outm[(size_t)i * F_HID + f] = f2bf(fmaxf(acc + bias[f], 0.f));
}

// ---------------- layer-2 aggregation + bias + log_softmax: wave per node ----------------
__global__ void k_agg2(const float* __restrict__ h, const int* __restrict__ csr,
                       const int* __restrict__ offs, const float* __restrict__ dinv,
                       const float* __restrict__ bias, float* __restrict__ outm, int N) {
    int warp = threadIdx.x >> 6, lane = threadIdx.x & 63;
    int i = blockIdx.x * 4 + warp;
    if (i >= N) return;
    float di = dinv[i];
    float acc = h[(size_t)i * F_OUT + lane] * di * di;
    int s = offs[i], e = offs[i + 1];
    for (int idx = s; idx < e; ++idx) {
        int j = csr[idx];
        acc += h[(size_t)j * F_OUT + lane] * (dinv[j] * di);
    }
    acc += bias[lane];
    float m = acc;
    #pragma unroll
    for (int o = 32; o >= 1; o >>= 1) m = fmaxf(m, __shfl_xor(m, o, 64));
    float ex = expf(acc - m);
    float ssum = ex;
    #pragma unroll
    for (int o = 32; o >= 1; o >>= 1) ssum += __shfl_xor(ssum, o, 64);
    outm[(size_t)i * F_OUT + lane] = acc - m - logf(ssum);
}

extern "C" void kernel_launch(void* const* d_in, const int* in_sizes, int n_in,
                              void* d_out, int out_size, void* d_ws, size_t ws_size,
                              hipStream_t stream) {
    const float* x  = (const float*)d_in[0];
    const int*   ei = (const int*)d_in[1];
    const float* W1 = (const float*)d_in[2];
    const float* b1 = (const float*)d_in[3];
    const float* W2 = (const float*)d_in[4];
    const float* b2 = (const float*)d_in[5];
    float* out = (float*)d_out;

    int N = in_sizes[0] / F_IN;   // 50000
    int E = in_sizes[1] / 2;      // 800000
    const int* src = ei;
    const int* dst = ei + E;

    // workspace layout (bytes all 16B-aligned by construction)
    ushort* xb  = (ushort*)d_ws;                        // N*512 bf16
    ushort* w1t = xb + (size_t)N * F_IN;                // 256*512
    ushort* w2t = w1t + F_HID * F_IN;                   // 64*256
    float*  h1  = (float*)(w2t + F_OUT * F_HID);        // N*256 fp32
    int*    deg = (int*)(h1 + (size_t)N * F_HID);       // N
    float*  dinv = (float*)(deg + N);                   // N
    int*    offs = (int*)(dinv + N);                    // N+1
    int*    cursor = offs + N + 1;                      // N
    int*    bsums  = cursor + N;                        // 256
    int*    csr    = bsums + 256;                       // E
    ushort* a1b = xb;    // alias: xb dead after GEMM1
    float*  h2  = h1;    // alias: h1 dead after agg1

    int nch = (N + 255) / 256;

    hipMemsetAsync(deg, 0, sizeof(int) * N, stream);
    k_deg <<<(E + 255) / 256, 256, 0, stream>>>(dst, deg, E);
    k_dinv<<<(N + 255) / 256, 256, 0, stream>>>(deg, dinv, N);
    k_scan1<<<nch, 256, 0, stream>>>(deg, offs, bsums, N);
    k_scan2<<<1, 256, 0, stream>>>(bsums, nch);
    k_scan3<<<nch, 256, 0, stream>>>(offs, bsums, cursor, N, E);
    k_fill<<<(E + 255) / 256, 256, 0, stream>>>(src, dst, cursor, csr, E);

    // casts
    int n8 = N * F_IN / 8;
    k_cast_bf16<<<(n8 + 255) / 256, 256, 0, stream>>>(x, xb, n8);
    k_tcast<<<(F_IN * F_HID + 255) / 256, 256, 0, stream>>>(W1, w1t, F_IN, F_HID);
    k_tcast<<<(F_HID * F_OUT + 255) / 256, 256, 0, stream>>>(W2, w2t, F_HID, F_OUT);

    // layer 1: GEMM (bf16 MFMA, 128x128 tile) + aggregate
    k_gemm_bf16<2, 2, 4, 4><<<dim3(F_HID / 128, (N + 127) / 128), 256, 0, stream>>>(
        xb, w1t, h1, N, F_IN, F_HID);
    k_agg1<<<N, 256, 0, stream>>>(h1, csr, offs, dinv, b1, a1b);

    // layer 2: GEMM (bf16 MFMA, 128x64 tile) + aggregate + log_softmax
    k_gemm_bf16<4, 1, 2, 4><<<dim3(F_OUT / 64, (N + 127) / 128), 256, 0, stream>>>(
        a1b, w2t, h2, N, F_HID, F_OUT);
    k_agg2<<<(N + 3) / 4, 256, 0, stream>>>(h2, csr, offs, dinv, b2, out, N);
}

// Round 3
// 292.350 us; speedup vs baseline: 2.4506x; 1.4702x over previous
//
#include <hip/hip_runtime.h>
#include <math.h>

#define F_IN  512
#define F_HID 256
#define F_OUT 64

typedef __attribute__((ext_vector_type(8))) short bf16x8;
typedef __attribute__((ext_vector_type(4))) short bf16x4;
typedef __attribute__((ext_vector_type(4))) float f32x4;

#define GLOBAL_AS __attribute__((address_space(1)))
#define LDS_AS    __attribute__((address_space(3)))

__device__ __forceinline__ void gload_lds16(const ushort* g, ushort* l) {
    __builtin_amdgcn_global_load_lds((const GLOBAL_AS uint32_t*)g,
                                     (LDS_AS uint32_t*)l, 16, 0, 0);
}

__device__ __forceinline__ ushort f2bf(float f) {
    union { float f; uint32_t u; } v; v.f = f;
    uint32_t r = (v.u + 0x7FFFu + ((v.u >> 16) & 1u)) >> 16;
    return (ushort)r;
}

__device__ __forceinline__ float bf2f(ushort u) {
    union { uint32_t u; float f; } v; v.u = ((uint32_t)u) << 16;
    return v.f;
}

// ---------------- degree / normalization ----------------
__global__ void k_deg(const int* __restrict__ dst, int* __restrict__ deg, int E) {
    int e = blockIdx.x * 256 + threadIdx.x;
    if (e < E) atomicAdd(&deg[dst[e]], 1);
}

__global__ void k_dinv(const int* __restrict__ deg, float* __restrict__ dinv, int N) {
    int i = blockIdx.x * 256 + threadIdx.x;
    if (i < N) dinv[i] = rsqrtf((float)(deg[i] + 1));  // +1 self loop
}

// ---------------- 2-level exclusive scan (chunk = 256) ----------------
__global__ void k_scan1(const int* __restrict__ deg, int* __restrict__ offs,
                        int* __restrict__ bsums, int N) {
    __shared__ int s[256];
    int tid = threadIdx.x;
    int i = blockIdx.x * 256 + tid;
    int v = (i < N) ? deg[i] : 0;
    s[tid] = v; __syncthreads();
    for (int d = 1; d < 256; d <<= 1) {
        int t = (tid >= d) ? s[tid - d] : 0;
        __syncthreads();
        s[tid] += t;
        __syncthreads();
    }
    if (i < N) offs[i] = s[tid] - v;
    if (tid == 255) bsums[blockIdx.x] = s[255];
}

__global__ void k_scan2(int* __restrict__ bsums, int n) {
    __shared__ int s[256];
    int tid = threadIdx.x;
    int v = (tid < n) ? bsums[tid] : 0;
    s[tid] = v; __syncthreads();
    for (int d = 1; d < 256; d <<= 1) {
        int t = (tid >= d) ? s[tid - d] : 0;
        __syncthreads();
        s[tid] += t;
        __syncthreads();
    }
    if (tid < n) bsums[tid] = s[tid] - v;
}

__global__ void k_scan3(int* __restrict__ offs, const int* __restrict__ bsums,
                        int* __restrict__ cursor, int N, int E) {
    int i = blockIdx.x * 256 + threadIdx.x;
    if (i < N) {
        int o = offs[i] + bsums[i >> 8];
        offs[i] = o;
        cursor[i] = o;
    }
    if (i == 0) offs[N] = E;
}

__global__ void k_fill(const int* __restrict__ src, const int* __restrict__ dst,
                       int* __restrict__ cursor, int* __restrict__ csr, int E) {
    int e = blockIdx.x * 256 + threadIdx.x;
    if (e < E) {
        int pos = atomicAdd(&cursor[dst[e]], 1);
        csr[pos] = src[e];
    }
}

// ---------------- casts ----------------
__global__ void k_cast_bf16(const float* __restrict__ in, ushort* __restrict__ outp, int n8) {
    int i = blockIdx.x * 256 + threadIdx.x;
    if (i >= n8) return;
    const float4* p = (const float4*)in + (size_t)i * 2;
    float4 v0 = p[0], v1 = p[1];
    bf16x8 o;
    o[0] = (short)f2bf(v0.x); o[1] = (short)f2bf(v0.y);
    o[2] = (short)f2bf(v0.z); o[3] = (short)f2bf(v0.w);
    o[4] = (short)f2bf(v1.x); o[5] = (short)f2bf(v1.y);
    o[6] = (short)f2bf(v1.z); o[7] = (short)f2bf(v1.w);
    *(bf16x8*)&outp[(size_t)i * 8] = o;
}

// in: [K][Nc] fp32  ->  out: [Nc][K] bf16
__global__ void k_tcast(const float* __restrict__ in, ushort* __restrict__ outp, int K, int Nc) {
    int idx = blockIdx.x * 256 + threadIdx.x;
    if (idx >= K * Nc) return;
    int n = idx / K, k = idx - n * K;
    outp[idx] = f2bf(in[(size_t)k * Nc + n]);
}

// ---------------- bf16 MFMA GEMM: C[M,Nc] = A[M,K] @ Bt[Nc,K]^T ----------------
// BK=32, 4 waves. OUT_BF16 selects bf16 vs fp32 C store.
template<int WR, int WC, int MR, int NR, bool OUT_BF16>
__global__ __launch_bounds__(256) void k_gemm_bf16(
        const ushort* __restrict__ A, const ushort* __restrict__ Bt,
        void* __restrict__ Cv, int M, int K, int Nc) {
    constexpr int BM = WR * MR * 16;
    constexpr int BN = WC * NR * 16;
    __shared__ ushort As[BM * 32];
    __shared__ ushort Bs[BN * 32];
    const int tid  = threadIdx.x;
    const int wave = tid >> 6, lane = tid & 63;
    const int wr = wave % WR, wc = wave / WR;
    const int brow = blockIdx.y * BM, bcol = blockIdx.x * BN;

    f32x4 acc[MR][NR];
    #pragma unroll
    for (int m = 0; m < MR; ++m)
        #pragma unroll
        for (int n = 0; n < NR; ++n) acc[m][n] = (f32x4){0.f, 0.f, 0.f, 0.f};

    const int srow = tid >> 2;
    const int scol = (tid & 3) * 8;
    const int kq  = (lane >> 4) * 8;
    const int rA0 = wr * MR * 16 + (lane & 15);
    const int rB0 = wc * NR * 16 + (lane & 15);

    for (int k0 = 0; k0 < K; k0 += 32) {
        #pragma unroll
        for (int l = 0; l < BM / 64; ++l) {
            int row = brow + l * 64 + srow;
            if (row >= M) row = M - 1;
            gload_lds16(&A[(size_t)row * K + k0 + scol], &As[l * 2048 + wave * 512]);
        }
        #pragma unroll
        for (int l = 0; l < BN / 64; ++l) {
            int row = bcol + l * 64 + srow;
            gload_lds16(&Bt[(size_t)row * K + k0 + scol], &Bs[l * 2048 + wave * 512]);
        }
        __syncthreads();
        bf16x8 af[MR], bfr[NR];
        #pragma unroll
        for (int m = 0; m < MR; ++m)
            af[m] = *(const bf16x8*)&As[(rA0 + m * 16) * 32 + kq];
        #pragma unroll
        for (int n = 0; n < NR; ++n)
            bfr[n] = *(const bf16x8*)&Bs[(rB0 + n * 16) * 32 + kq];
        #pragma unroll
        for (int m = 0; m < MR; ++m)
            #pragma unroll
            for (int n = 0; n < NR; ++n)
                acc[m][n] = __builtin_amdgcn_mfma_f32_16x16x32_bf16(af[m], bfr[n], acc[m][n], 0, 0, 0);
        __syncthreads();
    }

    const int crow0 = brow + wr * MR * 16 + (lane >> 4) * 4;
    const int ccol0 = bcol + wc * NR * 16 + (lane & 15);
    #pragma unroll
    for (int m = 0; m < MR; ++m)
        #pragma unroll
        for (int n = 0; n < NR; ++n)
            #pragma unroll
            for (int j = 0; j < 4; ++j) {
                int row = crow0 + m * 16 + j;
                if (row < M) {
                    if constexpr (OUT_BF16)
                        ((ushort*)Cv)[(size_t)row * Nc + ccol0 + n * 16] = f2bf(acc[m][n][j]);
                    else
                        ((float*)Cv)[(size_t)row * Nc + ccol0 + n * 16] = acc[m][n][j];
                }
            }
}

// ---------------- layer-1 aggregation: wave per node, lane owns 4 features ----------------
__global__ __launch_bounds__(256) void k_agg1(
        const ushort* __restrict__ h, const int* __restrict__ csr,
        const int* __restrict__ offs, const float* __restrict__ dinv,
        const float* __restrict__ bias, ushort* __restrict__ outm, int N) {
    int wave = threadIdx.x >> 6, lane = threadIdx.x & 63;
    int i = blockIdx.x * 4 + wave;
    if (i >= N) return;
    float di = dinv[i];
    float acc0, acc1, acc2, acc3;
    {
        bf16x4 hv = *(const bf16x4*)&h[(size_t)i * F_HID + lane * 4];
        float w = di * di;
        acc0 = bf2f((ushort)hv[0]) * w; acc1 = bf2f((ushort)hv[1]) * w;
        acc2 = bf2f((ushort)hv[2]) * w; acc3 = bf2f((ushort)hv[3]) * w;
    }
    int s = offs[i], e = offs[i + 1];
    for (int base = s; base < e; base += 64) {
        int t = base + lane;
        int j = (t < e) ? csr[t] : 0;
        float w = (t < e) ? dinv[j] * di : 0.f;
        int cnt = min(64, e - base);
        for (int u = 0; u < cnt; ++u) {
            int jj   = __shfl(j, u, 64);
            float ww = __shfl(w, u, 64);
            bf16x4 hv = *(const bf16x4*)&h[(size_t)jj * F_HID + lane * 4];
            acc0 += bf2f((ushort)hv[0]) * ww; acc1 += bf2f((ushort)hv[1]) * ww;
            acc2 += bf2f((ushort)hv[2]) * ww; acc3 += bf2f((ushort)hv[3]) * ww;
        }
    }
    const float4* bp = (const float4*)&bias[lane * 4];
    float4 bv = *bp;
    bf16x4 o;
    o[0] = (short)f2bf(fmaxf(acc0 + bv.x, 0.f));
    o[1] = (short)f2bf(fmaxf(acc1 + bv.y, 0.f));
    o[2] = (short)f2bf(fmaxf(acc2 + bv.z, 0.f));
    o[3] = (short)f2bf(fmaxf(acc3 + bv.w, 0.f));
    *(bf16x4*)&outm[(size_t)i * F_HID + lane * 4] = o;
}

// ---------------- layer-2 aggregation + bias + log_softmax: wave per node ----------------
__global__ __launch_bounds__(256) void k_agg2(
        const ushort* __restrict__ h, const int* __restrict__ csr,
        const int* __restrict__ offs, const float* __restrict__ dinv,
        const float* __restrict__ bias, float* __restrict__ outm, int N) {
    int wave = threadIdx.x >> 6, lane = threadIdx.x & 63;
    int i = blockIdx.x * 4 + wave;
    if (i >= N) return;
    float di = dinv[i];
    float acc = bf2f(h[(size_t)i * F_OUT + lane]) * di * di;
    int s = offs[i], e = offs[i + 1];
    for (int base = s; base < e; base += 64) {
        int t = base + lane;
        int j = (t < e) ? csr[t] : 0;
        float w = (t < e) ? dinv[j] * di : 0.f;
        int cnt = min(64, e - base);
        for (int u = 0; u < cnt; ++u) {
            int jj   = __shfl(j, u, 64);
            float ww = __shfl(w, u, 64);
            acc += bf2f(h[(size_t)jj * F_OUT + lane]) * ww;
        }
    }
    acc += bias[lane];
    float m = acc;
    #pragma unroll
    for (int o = 32; o >= 1; o >>= 1) m = fmaxf(m, __shfl_xor(m, o, 64));
    float ex = expf(acc - m);
    float ssum = ex;
    #pragma unroll
    for (int o = 32; o >= 1; o >>= 1) ssum += __shfl_xor(ssum, o, 64);
    outm[(size_t)i * F_OUT + lane] = acc - m - logf(ssum);
}

extern "C" void kernel_launch(void* const* d_in, const int* in_sizes, int n_in,
                              void* d_out, int out_size, void* d_ws, size_t ws_size,
                              hipStream_t stream) {
    const float* x  = (const float*)d_in[0];
    const int*   ei = (const int*)d_in[1];
    const float* W1 = (const float*)d_in[2];
    const float* b1 = (const float*)d_in[3];
    const float* W2 = (const float*)d_in[4];
    const float* b2 = (const float*)d_in[5];
    float* out = (float*)d_out;

    int N = in_sizes[0] / F_IN;   // 50000
    int E = in_sizes[1] / 2;      // 800000
    const int* src = ei;
    const int* dst = ei + E;

    // workspace layout
    ushort* xb  = (ushort*)d_ws;                        // N*512 bf16
    ushort* w1t = xb + (size_t)N * F_IN;                // 256*512
    ushort* w2t = w1t + F_HID * F_IN;                   // 64*256
    ushort* h1  = w2t + F_OUT * F_HID;                  // N*256 bf16
    int*    deg = (int*)(h1 + (size_t)N * F_HID);       // N
    float*  dinv = (float*)(deg + N);                   // N
    int*    offs = (int*)(dinv + N);                    // N+1
    int*    cursor = offs + N + 1;                      // N
    int*    bsums  = cursor + N;                        // 256
    int*    csr    = bsums + 256;                       // E
    ushort* a1b = xb;    // alias: xb dead after GEMM1
    ushort* h2  = h1;    // alias: h1 dead after agg1

    int nch = (N + 255) / 256;

    hipMemsetAsync(deg, 0, sizeof(int) * N, stream);
    k_deg <<<(E + 255) / 256, 256, 0, stream>>>(dst, deg, E);
    k_dinv<<<(N + 255) / 256, 256, 0, stream>>>(deg, dinv, N);
    k_scan1<<<nch, 256, 0, stream>>>(deg, offs, bsums, N);
    k_scan2<<<1, 256, 0, stream>>>(bsums, nch);
    k_scan3<<<nch, 256, 0, stream>>>(offs, bsums, cursor, N, E);
    k_fill<<<(E + 255) / 256, 256, 0, stream>>>(src, dst, cursor, csr, E);

    // casts
    int n8 = N * F_IN / 8;
    k_cast_bf16<<<(n8 + 255) / 256, 256, 0, stream>>>(x, xb, n8);
    k_tcast<<<(F_IN * F_HID + 255) / 256, 256, 0, stream>>>(W1, w1t, F_IN, F_HID);
    k_tcast<<<(F_HID * F_OUT + 255) / 256, 256, 0, stream>>>(W2, w2t, F_HID, F_OUT);

    // layer 1: GEMM (bf16 out) + aggregate (bf16 out)
    k_gemm_bf16<2, 2, 4, 4, true><<<dim3(F_HID / 128, (N + 127) / 128), 256, 0, stream>>>(
        xb, w1t, (void*)h1, N, F_IN, F_HID);
    k_agg1<<<(N + 3) / 4, 256, 0, stream>>>(h1, csr, offs, dinv, b1, a1b, N);

    // layer 2: GEMM (bf16 out) + aggregate + log_softmax
    k_gemm_bf16<4, 1, 2, 4, true><<<dim3(F_OUT / 64, (N + 127) / 128), 256, 0, stream>>>(
        a1b, w2t, (void*)h2, N, F_HID, F_OUT);
    k_agg2<<<(N + 3) / 4, 256, 0, stream>>>(h2, csr, offs, dinv, b2, out, N);
}

// Round 4
// 265.022 us; speedup vs baseline: 2.7033x; 1.1031x over previous
//
#include <hip/hip_runtime.h>
#include <math.h>

#define F_IN  512
#define F_HID 256
#define F_OUT 64

typedef __attribute__((ext_vector_type(8))) short bf16x8;
typedef __attribute__((ext_vector_type(4))) short bf16x4;
typedef __attribute__((ext_vector_type(4))) float f32x4;

#define GLOBAL_AS __attribute__((address_space(1)))
#define LDS_AS    __attribute__((address_space(3)))

__device__ __forceinline__ void gload_lds16(const ushort* g, ushort* l) {
    __builtin_amdgcn_global_load_lds((const GLOBAL_AS uint32_t*)g,
                                     (LDS_AS uint32_t*)l, 16, 0, 0);
}

__device__ __forceinline__ ushort f2bf(float f) {
    union { float f; uint32_t u; } v; v.f = f;
    uint32_t r = (v.u + 0x7FFFu + ((v.u >> 16) & 1u)) >> 16;
    return (ushort)r;
}

__device__ __forceinline__ float bf2f(ushort u) {
    union { uint32_t u; float f; } v; v.u = ((uint32_t)u) << 16;
    return v.f;
}

// ---------------- degree / normalization ----------------
__global__ void k_deg(const int* __restrict__ dst, int* __restrict__ deg, int E) {
    int e = blockIdx.x * 256 + threadIdx.x;
    if (e < E) atomicAdd(&deg[dst[e]], 1);
}

__global__ void k_dinv(const int* __restrict__ deg, float* __restrict__ dinv, int N) {
    int i = blockIdx.x * 256 + threadIdx.x;
    if (i < N) dinv[i] = rsqrtf((float)(deg[i] + 1));  // +1 self loop
}

// ---------------- 2-level exclusive scan (chunk = 256) ----------------
__global__ void k_scan1(const int* __restrict__ deg, int* __restrict__ offs,
                        int* __restrict__ bsums, int N) {
    __shared__ int s[256];
    int tid = threadIdx.x;
    int i = blockIdx.x * 256 + tid;
    int v = (i < N) ? deg[i] : 0;
    s[tid] = v; __syncthreads();
    for (int d = 1; d < 256; d <<= 1) {
        int t = (tid >= d) ? s[tid - d] : 0;
        __syncthreads();
        s[tid] += t;
        __syncthreads();
    }
    if (i < N) offs[i] = s[tid] - v;
    if (tid == 255) bsums[blockIdx.x] = s[255];
}

__global__ void k_scan2(int* __restrict__ bsums, int n) {
    __shared__ int s[256];
    int tid = threadIdx.x;
    int v = (tid < n) ? bsums[tid] : 0;
    s[tid] = v; __syncthreads();
    for (int d = 1; d < 256; d <<= 1) {
        int t = (tid >= d) ? s[tid - d] : 0;
        __syncthreads();
        s[tid] += t;
        __syncthreads();
    }
    if (tid < n) bsums[tid] = s[tid] - v;
}

__global__ void k_scan3(int* __restrict__ offs, const int* __restrict__ bsums,
                        int* __restrict__ cursor, int N, int E) {
    int i = blockIdx.x * 256 + threadIdx.x;
    if (i < N) {
        int o = offs[i] + bsums[i >> 8];
        offs[i] = o;
        cursor[i] = o;
    }
    if (i == 0) offs[N] = E;
}

__global__ void k_fill(const int* __restrict__ src, const int* __restrict__ dst,
                       int* __restrict__ cursor, int* __restrict__ csr, int E) {
    int e = blockIdx.x * 256 + threadIdx.x;
    if (e < E) {
        int pos = atomicAdd(&cursor[dst[e]], 1);
        csr[pos] = src[e];
    }
}

// ---------------- casts ----------------
__global__ void k_cast_bf16(const float* __restrict__ in, ushort* __restrict__ outp, int n8) {
    int i = blockIdx.x * 256 + threadIdx.x;
    if (i >= n8) return;
    const float4* p = (const float4*)in + (size_t)i * 2;
    float4 v0 = p[0], v1 = p[1];
    bf16x8 o;
    o[0] = (short)f2bf(v0.x); o[1] = (short)f2bf(v0.y);
    o[2] = (short)f2bf(v0.z); o[3] = (short)f2bf(v0.w);
    o[4] = (short)f2bf(v1.x); o[5] = (short)f2bf(v1.y);
    o[6] = (short)f2bf(v1.z); o[7] = (short)f2bf(v1.w);
    *(bf16x8*)&outp[(size_t)i * 8] = o;
}

// in: [K][Nc] fp32  ->  out: [Nc][K] bf16
__global__ void k_tcast(const float* __restrict__ in, ushort* __restrict__ outp, int K, int Nc) {
    int idx = blockIdx.x * 256 + threadIdx.x;
    if (idx >= K * Nc) return;
    int n = idx / K, k = idx - n * K;
    outp[idx] = f2bf(in[(size_t)k * Nc + n]);
}

// ---------------- bf16 MFMA GEMM: C[M,Nc] = A[M,K] @ Bt[Nc,K]^T ----------------
template<int WR, int WC, int MR, int NR, bool OUT_BF16>
__global__ __launch_bounds__(256) void k_gemm_bf16(
        const ushort* __restrict__ A, const ushort* __restrict__ Bt,
        void* __restrict__ Cv, int M, int K, int Nc) {
    constexpr int BM = WR * MR * 16;
    constexpr int BN = WC * NR * 16;
    __shared__ ushort As[BM * 32];
    __shared__ ushort Bs[BN * 32];
    const int tid  = threadIdx.x;
    const int wave = tid >> 6, lane = tid & 63;
    const int wr = wave % WR, wc = wave / WR;
    const int brow = blockIdx.y * BM, bcol = blockIdx.x * BN;

    f32x4 acc[MR][NR];
    #pragma unroll
    for (int m = 0; m < MR; ++m)
        #pragma unroll
        for (int n = 0; n < NR; ++n) acc[m][n] = (f32x4){0.f, 0.f, 0.f, 0.f};

    const int srow = tid >> 2;
    const int scol = (tid & 3) * 8;
    const int kq  = (lane >> 4) * 8;
    const int rA0 = wr * MR * 16 + (lane & 15);
    const int rB0 = wc * NR * 16 + (lane & 15);

    for (int k0 = 0; k0 < K; k0 += 32) {
        #pragma unroll
        for (int l = 0; l < BM / 64; ++l) {
            int row = brow + l * 64 + srow;
            if (row >= M) row = M - 1;
            gload_lds16(&A[(size_t)row * K + k0 + scol], &As[l * 2048 + wave * 512]);
        }
        #pragma unroll
        for (int l = 0; l < BN / 64; ++l) {
            int row = bcol + l * 64 + srow;
            gload_lds16(&Bt[(size_t)row * K + k0 + scol], &Bs[l * 2048 + wave * 512]);
        }
        __syncthreads();
        bf16x8 af[MR], bfr[NR];
        #pragma unroll
        for (int m = 0; m < MR; ++m)
            af[m] = *(const bf16x8*)&As[(rA0 + m * 16) * 32 + kq];
        #pragma unroll
        for (int n = 0; n < NR; ++n)
            bfr[n] = *(const bf16x8*)&Bs[(rB0 + n * 16) * 32 + kq];
        #pragma unroll
        for (int m = 0; m < MR; ++m)
            #pragma unroll
            for (int n = 0; n < NR; ++n)
                acc[m][n] = __builtin_amdgcn_mfma_f32_16x16x32_bf16(af[m], bfr[n], acc[m][n], 0, 0, 0);
        __syncthreads();
    }

    const int crow0 = brow + wr * MR * 16 + (lane >> 4) * 4;
    const int ccol0 = bcol + wc * NR * 16 + (lane & 15);
    #pragma unroll
    for (int m = 0; m < MR; ++m)
        #pragma unroll
        for (int n = 0; n < NR; ++n)
            #pragma unroll
            for (int j = 0; j < 4; ++j) {
                int row = crow0 + m * 16 + j;
                if (row < M) {
                    if constexpr (OUT_BF16)
                        ((ushort*)Cv)[(size_t)row * Nc + ccol0 + n * 16] = f2bf(acc[m][n][j]);
                    else
                        ((float*)Cv)[(size_t)row * Nc + ccol0 + n * 16] = acc[m][n][j];
                }
            }
}

// ---------------- layer-1 aggregation: wave per node, lane owns 4 features ----------------
// 8x unrolled edge loop: 8 independent row-gathers in flight per wave.
__global__ __launch_bounds__(256) void k_agg1(
        const ushort* __restrict__ h, const int* __restrict__ csr,
        const int* __restrict__ offs, const float* __restrict__ dinv,
        const float* __restrict__ bias, ushort* __restrict__ outm, int N) {
    int wave = threadIdx.x >> 6, lane = threadIdx.x & 63;
    int i = blockIdx.x * 4 + wave;
    if (i >= N) return;
    float di = dinv[i];
    float acc0, acc1, acc2, acc3;
    {
        bf16x4 hv = *(const bf16x4*)&h[(size_t)i * F_HID + lane * 4];
        float w = di * di;
        acc0 = bf2f((ushort)hv[0]) * w; acc1 = bf2f((ushort)hv[1]) * w;
        acc2 = bf2f((ushort)hv[2]) * w; acc3 = bf2f((ushort)hv[3]) * w;
    }
    int s = offs[i], e = offs[i + 1];
    for (int base = s; base < e; base += 64) {
        int t = base + lane;
        int j = (t < e) ? csr[t] : 0;
        float w = (t < e) ? dinv[j] * di : 0.f;
        int cnt = min(64, e - base);
        int u = 0;
        for (; u + 8 <= cnt; u += 8) {
            bf16x4 hv[8]; float ww[8];
            #pragma unroll
            for (int q = 0; q < 8; ++q) {
                int jj = __shfl(j, u + q, 64);
                ww[q] = __shfl(w, u + q, 64);
                hv[q] = *(const bf16x4*)&h[(size_t)jj * F_HID + lane * 4];
            }
            #pragma unroll
            for (int q = 0; q < 8; ++q) {
                acc0 += bf2f((ushort)hv[q][0]) * ww[q];
                acc1 += bf2f((ushort)hv[q][1]) * ww[q];
                acc2 += bf2f((ushort)hv[q][2]) * ww[q];
                acc3 += bf2f((ushort)hv[q][3]) * ww[q];
            }
        }
        for (; u < cnt; ++u) {
            int jj = __shfl(j, u, 64);
            float ww = __shfl(w, u, 64);
            bf16x4 hv = *(const bf16x4*)&h[(size_t)jj * F_HID + lane * 4];
            acc0 += bf2f((ushort)hv[0]) * ww; acc1 += bf2f((ushort)hv[1]) * ww;
            acc2 += bf2f((ushort)hv[2]) * ww; acc3 += bf2f((ushort)hv[3]) * ww;
        }
    }
    const float4* bp = (const float4*)&bias[lane * 4];
    float4 bv = *bp;
    bf16x4 o;
    o[0] = (short)f2bf(fmaxf(acc0 + bv.x, 0.f));
    o[1] = (short)f2bf(fmaxf(acc1 + bv.y, 0.f));
    o[2] = (short)f2bf(fmaxf(acc2 + bv.z, 0.f));
    o[3] = (short)f2bf(fmaxf(acc3 + bv.w, 0.f));
    *(bf16x4*)&outm[(size_t)i * F_HID + lane * 4] = o;
}

// ---------------- layer-2 aggregation + bias + log_softmax: wave per node ----------------
__global__ __launch_bounds__(256) void k_agg2(
        const ushort* __restrict__ h, const int* __restrict__ csr,
        const int* __restrict__ offs, const float* __restrict__ dinv,
        const float* __restrict__ bias, float* __restrict__ outm, int N) {
    int wave = threadIdx.x >> 6, lane = threadIdx.x & 63;
    int i = blockIdx.x * 4 + wave;
    if (i >= N) return;
    float di = dinv[i];
    float acc = bf2f(h[(size_t)i * F_OUT + lane]) * di * di;
    int s = offs[i], e = offs[i + 1];
    for (int base = s; base < e; base += 64) {
        int t = base + lane;
        int j = (t < e) ? csr[t] : 0;
        float w = (t < e) ? dinv[j] * di : 0.f;
        int cnt = min(64, e - base);
        int u = 0;
        for (; u + 8 <= cnt; u += 8) {
            float hv[8], ww[8];
            #pragma unroll
            for (int q = 0; q < 8; ++q) {
                int jj = __shfl(j, u + q, 64);
                ww[q] = __shfl(w, u + q, 64);
                hv[q] = bf2f(h[(size_t)jj * F_OUT + lane]);
            }
            #pragma unroll
            for (int q = 0; q < 8; ++q) acc += hv[q] * ww[q];
        }
        for (; u < cnt; ++u) {
            int jj = __shfl(j, u, 64);
            float ww = __shfl(w, u, 64);
            acc += bf2f(h[(size_t)jj * F_OUT + lane]) * ww;
        }
    }
    acc += bias[lane];
    float m = acc;
    #pragma unroll
    for (int o = 32; o >= 1; o >>= 1) m = fmaxf(m, __shfl_xor(m, o, 64));
    float ex = expf(acc - m);
    float ssum = ex;
    #pragma unroll
    for (int o = 32; o >= 1; o >>= 1) ssum += __shfl_xor(ssum, o, 64);
    outm[(size_t)i * F_OUT + lane] = acc - m - logf(ssum);
}

extern "C" void kernel_launch(void* const* d_in, const int* in_sizes, int n_in,
                              void* d_out, int out_size, void* d_ws, size_t ws_size,
                              hipStream_t stream) {
    const float* x  = (const float*)d_in[0];
    const int*   ei = (const int*)d_in[1];
    const float* W1 = (const float*)d_in[2];
    const float* b1 = (const float*)d_in[3];
    const float* W2 = (const float*)d_in[4];
    const float* b2 = (const float*)d_in[5];
    float* out = (float*)d_out;

    int N = in_sizes[0] / F_IN;   // 50000
    int E = in_sizes[1] / 2;      // 800000
    const int* src = ei;
    const int* dst = ei + E;

    // workspace layout
    ushort* xb  = (ushort*)d_ws;                        // N*512 bf16
    ushort* w1t = xb + (size_t)N * F_IN;                // 256*512
    ushort* w2t = w1t + F_HID * F_IN;                   // 64*256
    ushort* h1  = w2t + F_OUT * F_HID;                  // N*256 bf16
    int*    deg = (int*)(h1 + (size_t)N * F_HID);       // N
    float*  dinv = (float*)(deg + N);                   // N
    int*    offs = (int*)(dinv + N);                    // N+1
    int*    cursor = offs + N + 1;                      // N
    int*    bsums  = cursor + N;                        // 256
    int*    csr    = bsums + 256;                       // E
    ushort* a1b = xb;    // alias: xb dead after GEMM1
    ushort* h2  = h1;    // alias: h1 dead after agg1

    int nch = (N + 255) / 256;

    hipMemsetAsync(deg, 0, sizeof(int) * N, stream);
    k_deg <<<(E + 255) / 256, 256, 0, stream>>>(dst, deg, E);
    k_dinv<<<(N + 255) / 256, 256, 0, stream>>>(deg, dinv, N);
    k_scan1<<<nch, 256, 0, stream>>>(deg, offs, bsums, N);
    k_scan2<<<1, 256, 0, stream>>>(bsums, nch);
    k_scan3<<<nch, 256, 0, stream>>>(offs, bsums, cursor, N, E);
    k_fill<<<(E + 255) / 256, 256, 0, stream>>>(src, dst, cursor, csr, E);

    // casts
    int n8 = N * F_IN / 8;
    k_cast_bf16<<<(n8 + 255) / 256, 256, 0, stream>>>(x, xb, n8);
    k_tcast<<<(F_IN * F_HID + 255) / 256, 256, 0, stream>>>(W1, w1t, F_IN, F_HID);
    k_tcast<<<(F_HID * F_OUT + 255) / 256, 256, 0, stream>>>(W2, w2t, F_HID, F_OUT);

    // layer 1: GEMM (bf16 out) + aggregate (bf16 out)
    k_gemm_bf16<2, 2, 4, 4, true><<<dim3(F_HID / 128, (N + 127) / 128), 256, 0, stream>>>(
        xb, w1t, (void*)h1, N, F_IN, F_HID);
    k_agg1<<<(N + 3) / 4, 256, 0, stream>>>(h1, csr, offs, dinv, b1, a1b, N);

    // layer 2: GEMM (bf16 out) + aggregate + log_softmax
    k_gemm_bf16<4, 1, 2, 4, true><<<dim3(F_OUT / 64, (N + 127) / 128), 256, 0, stream>>>(
        a1b, w2t, (void*)h2, N, F_HID, F_OUT);
    k_agg2<<<(N + 3) / 4, 256, 0, stream>>>(h2, csr, offs, dinv, b2, out, N);
}

// Round 5
// 265.003 us; speedup vs baseline: 2.7035x; 1.0001x over previous
//
#include <hip/hip_runtime.h>
#include <math.h>

#define F_IN  512
#define F_HID 256
#define F_OUT 64

typedef __attribute__((ext_vector_type(8))) short bf16x8;
typedef __attribute__((ext_vector_type(4))) short bf16x4;
typedef __attribute__((ext_vector_type(4))) float f32x4;

#define GLOBAL_AS __attribute__((address_space(1)))
#define LDS_AS    __attribute__((address_space(3)))

__device__ __forceinline__ void gload_lds16(const ushort* g, ushort* l) {
    __builtin_amdgcn_global_load_lds((const GLOBAL_AS uint32_t*)g,
                                     (LDS_AS uint32_t*)l, 16, 0, 0);
}

__device__ __forceinline__ ushort f2bf(float f) {
    union { float f; uint32_t u; } v; v.f = f;
    uint32_t r = (v.u + 0x7FFFu + ((v.u >> 16) & 1u)) >> 16;
    return (ushort)r;
}

__device__ __forceinline__ float bf2f(ushort u) {
    union { uint32_t u; float f; } v; v.u = ((uint32_t)u) << 16;
    return v.f;
}

// ---------------- degree / normalization ----------------
__global__ void k_deg(const int* __restrict__ dst, int* __restrict__ deg, int E) {
    int e = blockIdx.x * 256 + threadIdx.x;
    if (e < E) atomicAdd(&deg[dst[e]], 1);
}

__global__ void k_dinv(const int* __restrict__ deg, float* __restrict__ dinv, int N) {
    int i = blockIdx.x * 256 + threadIdx.x;
    if (i < N) dinv[i] = rsqrtf((float)(deg[i] + 1));  // +1 self loop
}

// ---------------- 2-level exclusive scan (chunk = 256) ----------------
__global__ void k_scan1(const int* __restrict__ deg, int* __restrict__ offs,
                        int* __restrict__ bsums, int N) {
    __shared__ int s[256];
    int tid = threadIdx.x;
    int i = blockIdx.x * 256 + tid;
    int v = (i < N) ? deg[i] : 0;
    s[tid] = v; __syncthreads();
    for (int d = 1; d < 256; d <<= 1) {
        int t = (tid >= d) ? s[tid - d] : 0;
        __syncthreads();
        s[tid] += t;
        __syncthreads();
    }
    if (i < N) offs[i] = s[tid] - v;
    if (tid == 255) bsums[blockIdx.x] = s[255];
}

__global__ void k_scan2(int* __restrict__ bsums, int n) {
    __shared__ int s[256];
    int tid = threadIdx.x;
    int v = (tid < n) ? bsums[tid] : 0;
    s[tid] = v; __syncthreads();
    for (int d = 1; d < 256; d <<= 1) {
        int t = (tid >= d) ? s[tid - d] : 0;
        __syncthreads();
        s[tid] += t;
        __syncthreads();
    }
    if (tid < n) bsums[tid] = s[tid] - v;
}

__global__ void k_scan3(int* __restrict__ offs, const int* __restrict__ bsums,
                        int* __restrict__ cursor, int2* __restrict__ jw, int N, int E) {
    int i = blockIdx.x * 256 + threadIdx.x;
    if (i < N) {
        int o = offs[i] + bsums[i >> 8];
        offs[i] = o;
        cursor[i] = o;
    }
    if (i == 0) offs[N] = E;
    if (i < 8) jw[E + i] = make_int2(0, 0);   // pad: row 0, weight 0
}

// fill packed (src_index, dinv[src]) per CSR slot
__global__ void k_fill(const int* __restrict__ src, const int* __restrict__ dst,
                       int* __restrict__ cursor, int2* __restrict__ jw,
                       const float* __restrict__ dinv, int E) {
    int e = blockIdx.x * 256 + threadIdx.x;
    if (e < E) {
        int s = src[e];
        int pos = atomicAdd(&cursor[dst[e]], 1);
        jw[pos] = make_int2(s, __float_as_int(dinv[s]));
    }
}

// ---------------- casts ----------------
__global__ void k_cast_bf16(const float* __restrict__ in, ushort* __restrict__ outp, int n8) {
    int i = blockIdx.x * 256 + threadIdx.x;
    if (i >= n8) return;
    const float4* p = (const float4*)in + (size_t)i * 2;
    float4 v0 = p[0], v1 = p[1];
    bf16x8 o;
    o[0] = (short)f2bf(v0.x); o[1] = (short)f2bf(v0.y);
    o[2] = (short)f2bf(v0.z); o[3] = (short)f2bf(v0.w);
    o[4] = (short)f2bf(v1.x); o[5] = (short)f2bf(v1.y);
    o[6] = (short)f2bf(v1.z); o[7] = (short)f2bf(v1.w);
    *(bf16x8*)&outp[(size_t)i * 8] = o;
}

// in: [K][Nc] fp32  ->  out: [Nc][K] bf16
__global__ void k_tcast(const float* __restrict__ in, ushort* __restrict__ outp, int K, int Nc) {
    int idx = blockIdx.x * 256 + threadIdx.x;
    if (idx >= K * Nc) return;
    int n = idx / K, k = idx - n * K;
    outp[idx] = f2bf(in[(size_t)k * Nc + n]);
}

// ---------------- bf16 MFMA GEMM: C[M,Nc] = A[M,K] @ Bt[Nc,K]^T ----------------
template<int WR, int WC, int MR, int NR, bool OUT_BF16>
__global__ __launch_bounds__(256) void k_gemm_bf16(
        const ushort* __restrict__ A, const ushort* __restrict__ Bt,
        void* __restrict__ Cv, int M, int K, int Nc) {
    constexpr int BM = WR * MR * 16;
    constexpr int BN = WC * NR * 16;
    __shared__ ushort As[BM * 32];
    __shared__ ushort Bs[BN * 32];
    const int tid  = threadIdx.x;
    const int wave = tid >> 6, lane = tid & 63;
    const int wr = wave % WR, wc = wave / WR;
    const int brow = blockIdx.y * BM, bcol = blockIdx.x * BN;

    f32x4 acc[MR][NR];
    #pragma unroll
    for (int m = 0; m < MR; ++m)
        #pragma unroll
        for (int n = 0; n < NR; ++n) acc[m][n] = (f32x4){0.f, 0.f, 0.f, 0.f};

    const int srow = tid >> 2;
    const int scol = (tid & 3) * 8;
    const int kq  = (lane >> 4) * 8;
    const int rA0 = wr * MR * 16 + (lane & 15);
    const int rB0 = wc * NR * 16 + (lane & 15);

    for (int k0 = 0; k0 < K; k0 += 32) {
        #pragma unroll
        for (int l = 0; l < BM / 64; ++l) {
            int row = brow + l * 64 + srow;
            if (row >= M) row = M - 1;
            gload_lds16(&A[(size_t)row * K + k0 + scol], &As[l * 2048 + wave * 512]);
        }
        #pragma unroll
        for (int l = 0; l < BN / 64; ++l) {
            int row = bcol + l * 64 + srow;
            gload_lds16(&Bt[(size_t)row * K + k0 + scol], &Bs[l * 2048 + wave * 512]);
        }
        __syncthreads();
        bf16x8 af[MR], bfr[NR];
        #pragma unroll
        for (int m = 0; m < MR; ++m)
            af[m] = *(const bf16x8*)&As[(rA0 + m * 16) * 32 + kq];
        #pragma unroll
        for (int n = 0; n < NR; ++n)
            bfr[n] = *(const bf16x8*)&Bs[(rB0 + n * 16) * 32 + kq];
        #pragma unroll
        for (int m = 0; m < MR; ++m)
            #pragma unroll
            for (int n = 0; n < NR; ++n)
                acc[m][n] = __builtin_amdgcn_mfma_f32_16x16x32_bf16(af[m], bfr[n], acc[m][n], 0, 0, 0);
        __syncthreads();
    }

    const int crow0 = brow + wr * MR * 16 + (lane >> 4) * 4;
    const int ccol0 = bcol + wc * NR * 16 + (lane & 15);
    #pragma unroll
    for (int m = 0; m < MR; ++m)
        #pragma unroll
        for (int n = 0; n < NR; ++n)
            #pragma unroll
            for (int j = 0; j < 4; ++j) {
                int row = crow0 + m * 16 + j;
                if (row < M) {
                    if constexpr (OUT_BF16)
                        ((ushort*)Cv)[(size_t)row * Nc + ccol0 + n * 16] = f2bf(acc[m][n][j]);
                    else
                        ((float*)Cv)[(size_t)row * Nc + ccol0 + n * 16] = acc[m][n][j];
                }
            }
}

// ---------------- layer-1 aggregation: wave per node, lane owns 4 features ----------------
// shfl-free: uniform 8B (j,w) loads + 8 independent row-gather chains per group.
__global__ __launch_bounds__(256) void k_agg1(
        const ushort* __restrict__ h, const int2* __restrict__ jw,
        const int* __restrict__ offs, const float* __restrict__ dinv,
        const float* __restrict__ bias, ushort* __restrict__ outm, int N) {
    int wave = threadIdx.x >> 6, lane = threadIdx.x & 63;
    int i = blockIdx.x * 4 + wave;
    if (i >= N) return;
    float di = dinv[i];
    float acc0, acc1, acc2, acc3;
    {
        bf16x4 hv = *(const bf16x4*)&h[(size_t)i * F_HID + lane * 4];
        float w = di * di;
        acc0 = bf2f((ushort)hv[0]) * w; acc1 = bf2f((ushort)hv[1]) * w;
        acc2 = bf2f((ushort)hv[2]) * w; acc3 = bf2f((ushort)hv[3]) * w;
    }
    int s = offs[i], e = offs[i + 1];
    for (int u = s; u < e; u += 8) {
        int2 a[8];
        #pragma unroll
        for (int q = 0; q < 8; ++q) a[q] = jw[u + q];      // may overrun into next node / pad
        bf16x4 hv[8];
        #pragma unroll
        for (int q = 0; q < 8; ++q)
            hv[q] = *(const bf16x4*)&h[(size_t)a[q].x * F_HID + lane * 4];
        #pragma unroll
        for (int q = 0; q < 8; ++q) {
            float ww = (u + q < e) ? __int_as_float(a[q].y) * di : 0.f;
            acc0 += bf2f((ushort)hv[q][0]) * ww;
            acc1 += bf2f((ushort)hv[q][1]) * ww;
            acc2 += bf2f((ushort)hv[q][2]) * ww;
            acc3 += bf2f((ushort)hv[q][3]) * ww;
        }
    }
    const float4* bp = (const float4*)&bias[lane * 4];
    float4 bv = *bp;
    bf16x4 o;
    o[0] = (short)f2bf(fmaxf(acc0 + bv.x, 0.f));
    o[1] = (short)f2bf(fmaxf(acc1 + bv.y, 0.f));
    o[2] = (short)f2bf(fmaxf(acc2 + bv.z, 0.f));
    o[3] = (short)f2bf(fmaxf(acc3 + bv.w, 0.f));
    *(bf16x4*)&outm[(size_t)i * F_HID + lane * 4] = o;
}

// ---------------- layer-2 aggregation + bias + log_softmax: wave per node ----------------
__global__ __launch_bounds__(256) void k_agg2(
        const ushort* __restrict__ h, const int2* __restrict__ jw,
        const int* __restrict__ offs, const float* __restrict__ dinv,
        const float* __restrict__ bias, float* __restrict__ outm, int N) {
    int wave = threadIdx.x >> 6, lane = threadIdx.x & 63;
    int i = blockIdx.x * 4 + wave;
    if (i >= N) return;
    float di = dinv[i];
    float acc = bf2f(h[(size_t)i * F_OUT + lane]) * di * di;
    int s = offs[i], e = offs[i + 1];
    for (int u = s; u < e; u += 8) {
        int2 a[8];
        #pragma unroll
        for (int q = 0; q < 8; ++q) a[q] = jw[u + q];
        float hv[8];
        #pragma unroll
        for (int q = 0; q < 8; ++q)
            hv[q] = bf2f(h[(size_t)a[q].x * F_OUT + lane]);
        #pragma unroll
        for (int q = 0; q < 8; ++q) {
            float ww = (u + q < e) ? __int_as_float(a[q].y) * di : 0.f;
            acc += hv[q] * ww;
        }
    }
    acc += bias[lane];
    float m = acc;
    #pragma unroll
    for (int o = 32; o >= 1; o >>= 1) m = fmaxf(m, __shfl_xor(m, o, 64));
    float ex = expf(acc - m);
    float ssum = ex;
    #pragma unroll
    for (int o = 32; o >= 1; o >>= 1) ssum += __shfl_xor(ssum, o, 64);
    outm[(size_t)i * F_OUT + lane] = acc - m - logf(ssum);
}

extern "C" void kernel_launch(void* const* d_in, const int* in_sizes, int n_in,
                              void* d_out, int out_size, void* d_ws, size_t ws_size,
                              hipStream_t stream) {
    const float* x  = (const float*)d_in[0];
    const int*   ei = (const int*)d_in[1];
    const float* W1 = (const float*)d_in[2];
    const float* b1 = (const float*)d_in[3];
    const float* W2 = (const float*)d_in[4];
    const float* b2 = (const float*)d_in[5];
    float* out = (float*)d_out;

    int N = in_sizes[0] / F_IN;   // 50000
    int E = in_sizes[1] / 2;      // 800000
    const int* src = ei;
    const int* dst = ei + E;

    // workspace layout
    ushort* xb  = (ushort*)d_ws;                        // N*512 bf16
    ushort* w1t = xb + (size_t)N * F_IN;                // 256*512
    ushort* w2t = w1t + F_HID * F_IN;                   // 64*256
    ushort* h1  = w2t + F_OUT * F_HID;                  // N*256 bf16
    int*    deg = (int*)(h1 + (size_t)N * F_HID);       // N
    float*  dinv = (float*)(deg + N);                   // N
    int*    offs = (int*)(dinv + N);                    // N+1
    int*    cursor = offs + N + 1;                      // N
    int*    bsums  = cursor + N;                        // 256
    int2*   jw     = (int2*)(bsums + 256 + 1);          // E+8 (8B aligned: odd pad keeps 8B alignment)
    // ensure 8-byte alignment of jw
    jw = (int2*)(((uintptr_t)(bsums + 256) + 7) & ~(uintptr_t)7);
    ushort* a1b = xb;    // alias: xb dead after GEMM1
    ushort* h2  = h1;    // alias: h1 dead after agg1

    int nch = (N + 255) / 256;

    hipMemsetAsync(deg, 0, sizeof(int) * N, stream);
    k_deg <<<(E + 255) / 256, 256, 0, stream>>>(dst, deg, E);
    k_dinv<<<(N + 255) / 256, 256, 0, stream>>>(deg, dinv, N);
    k_scan1<<<nch, 256, 0, stream>>>(deg, offs, bsums, N);
    k_scan2<<<1, 256, 0, stream>>>(bsums, nch);
    k_scan3<<<nch, 256, 0, stream>>>(offs, bsums, cursor, jw, N, E);
    k_fill<<<(E + 255) / 256, 256, 0, stream>>>(src, dst, cursor, jw, dinv, E);

    // casts
    int n8 = N * F_IN / 8;
    k_cast_bf16<<<(n8 + 255) / 256, 256, 0, stream>>>(x, xb, n8);
    k_tcast<<<(F_IN * F_HID + 255) / 256, 256, 0, stream>>>(W1, w1t, F_IN, F_HID);
    k_tcast<<<(F_HID * F_OUT + 255) / 256, 256, 0, stream>>>(W2, w2t, F_HID, F_OUT);

    // layer 1: GEMM (bf16 out) + aggregate (bf16 out)
    k_gemm_bf16<2, 2, 4, 4, true><<<dim3(F_HID / 128, (N + 127) / 128), 256, 0, stream>>>(
        xb, w1t, (void*)h1, N, F_IN, F_HID);
    k_agg1<<<(N + 3) / 4, 256, 0, stream>>>(h1, jw, offs, dinv, b1, a1b, N);

    // layer 2: GEMM (bf16 out) + aggregate + log_softmax
    k_gemm_bf16<4, 1, 2, 4, true><<<dim3(F_OUT / 64, (N + 127) / 128), 256, 0, stream>>>(
        a1b, w2t, (void*)h2, N, F_HID, F_OUT);
    k_agg2<<<(N + 3) / 4, 256, 0, stream>>>(h2, jw, offs, dinv, b2, out, N);
}